// Round 8
// baseline (1163.060 us; speedup 1.0000x reference)
//
#include <hip/hip_runtime.h>
#include <hip/hip_bf16.h>
#include <stdint.h>

// ---------------- types ----------------
typedef float    f32x16 __attribute__((ext_vector_type(16)));
typedef float    f32x4  __attribute__((ext_vector_type(4)));
typedef __bf16   bf16x8 __attribute__((ext_vector_type(8)));
typedef uint32_t u32x4  __attribute__((ext_vector_type(4)));

// ---------------- workspace layout (bytes) ----------------
#define WS_QG    0
#define WS_KG    8388608
#define WS_VTG   16777216
#define WS_ATTN  25165824
#define WS_WT    33554432
#define WS_WUT   33751040

__device__ __forceinline__ f32x16 zero16(){
  f32x16 z;
  #pragma unroll
  for (int i = 0; i < 16; ++i) z[i] = 0.0f;
  return z;
}

__device__ __forceinline__ uint16_t bf16b(float v){
  return __builtin_bit_cast(uint16_t, __float2bfloat16(v));
}

__device__ __forceinline__ uint32_t pk2(float a, float b){
  return (uint32_t)bf16b(a) | ((uint32_t)bf16b(b) << 16);
}

// packed f32->bf16 pair in ONE instruction (RNE, same as __float2bfloat16)
__device__ __forceinline__ uint32_t cvtpk(float a, float b){
  uint32_t r;
  asm("v_cvt_pk_bf16_f32 %0, %1, %2" : "=v"(r) : "v"(a), "v"(b));
  return r;
}

__device__ __forceinline__ void plswap(uint32_t &a, uint32_t &b){
  asm volatile("v_permlane32_swap_b32 %0, %1" : "+v"(a), "+v"(b));
}

__device__ __forceinline__ float sum16(const f32x16& s){
  float a0 = (s[0]+s[1]) + (s[2]+s[3]),   a1 = (s[4]+s[5]) + (s[6]+s[7]);
  float a2 = (s[8]+s[9]) + (s[10]+s[11]), a3 = (s[12]+s[13]) + (s[14]+s[15]);
  return (a0 + a1) + (a2 + a3);
}

// raw barrier: drain own LDS ops, sync, compiler fence (vmcnt NOT drained).
__device__ __forceinline__ void bar_ws(){
  asm volatile("s_waitcnt lgkmcnt(0)" ::: "memory");
  __builtin_amdgcn_s_barrier();
  asm volatile("" ::: "memory");
}

// ---------------- kernel 0: weight prep ----------------
// Wf fragment layout: [mm][cb][ks][half][lane][8] so qkv_proj loads are
// fully coalesced (lane-contiguous 16B chunks).
__global__ void prep_w(const float* __restrict__ Wq, const float* __restrict__ Wk,
                       const float* __restrict__ Wv, const float* __restrict__ Wu,
                       char* __restrict__ ws){
  int tid = blockIdx.x * 256 + threadIdx.x;   // grid 512*256 = 131072
  if (tid < 98304){
    int j  = tid & 7;
    int ln = (tid >> 3) & 63;
    int hf = (tid >> 9) & 1;
    int ks = (tid >> 10) & 3;
    int cb = (tid >> 12) & 7;
    int mm = tid >> 15;
    int colW = ln & 31, hiW = ln >> 5;
    int k = ks*16 + hiW*8 + j;
    int e = cb*64 + colW + 32*hf;
    const float* W = (mm == 0) ? Wq : (mm == 1 ? Wk : Wv);
    float v = W[k*512 + e];
    if (mm == 0) v *= 0.18033688011112042f;   // (1/8) * log2(e) folded into Q
    ((uint16_t*)(ws + WS_WT))[tid] = bf16b(v);
  } else {
    int idx = tid - 98304;
    int c = idx & 63, e = idx >> 6;
    ((uint16_t*)(ws + WS_WUT))[c*512 + e] = bf16b(Wu[e*64 + c]);
  }
}

// ---------------- kernel 1: QKV projection (MFMA) ----------------
// grid 512: rt = x8*32 + (o>>1), half = o&1; block = 4 waves, af computed
// once per wave, 3 (mm,cb) tasks per wave with coalesced fragment W loads.
__global__ __launch_bounds__(256,2) void qkv_proj(const float* __restrict__ x,
                                                  char* __restrict__ ws){
  const int lane = threadIdx.x & 63;
  const int widx = threadIdx.x >> 6;
  const int x8 = blockIdx.x & 7;
  const int o  = blockIdx.x >> 3;        // 0..63
  const int rt   = x8*32 + (o >> 1);     // 0..255, XCD-pinned
  const int half = o & 1;
  const int col  = lane & 31, hi = lane >> 5;

  __shared__ __align__(16) uint16_t tbuf[4][2560];   // per-wave transpose buffer

  const uint16_t* Wf = (const uint16_t*)(ws + WS_WT);

  // A: row = lane&31, k = (lane>>5)*8 + i (+16*ks)  — computed ONCE
  bf16x8 af[4];
  {
    const float* xr = x + (size_t)(rt*32 + col)*64 + hi*8;
    #pragma unroll
    for (int ks = 0; ks < 4; ++ks){
      float4 a0 = *(const float4*)(xr + ks*16);
      float4 a1 = *(const float4*)(xr + ks*16 + 4);
      uint4 u;
      u.x = pk2(a0.x, a0.y); u.y = pk2(a0.z, a0.w);
      u.z = pk2(a1.x, a1.y); u.w = pk2(a1.z, a1.w);
      af[ks] = __builtin_bit_cast(bf16x8, u);
    }
  }

  uint16_t* Qg  = (uint16_t*)(ws + WS_QG);
  uint16_t* Kg  = (uint16_t*)(ws + WS_KG);
  uint16_t* Vtg = (uint16_t*)(ws + WS_VTG);
  uint16_t* tb  = tbuf[widx];
  const int b     = (rt*32) >> 12;
  const int ltok0 = (rt*32) & 4095;

  #pragma unroll
  for (int ti = 0; ti < 3; ++ti){
    const int rem = half*12 + widx*3 + ti;   // 0..23
    const int mm = rem >> 3, cb = rem & 7;

    f32x16 acc0 = zero16(), acc1 = zero16();
    {
      const uint16_t* wp = Wf + (size_t)((mm*8 + cb)*4)*1024 + lane*8;
      #pragma unroll
      for (int ks = 0; ks < 4; ++ks){
        bf16x8 b0 = *(const bf16x8*)(wp + ks*1024);
        bf16x8 b1 = *(const bf16x8*)(wp + ks*1024 + 512);
        acc0 = __builtin_amdgcn_mfma_f32_32x32x16_bf16(af[ks], b0, acc0, 0, 0, 0);
        acc1 = __builtin_amdgcn_mfma_f32_32x32x16_bf16(af[ks], b1, acc1, 0, 0, 0);
      }
    }

    // D: col = lane&31, row(tok) = (r&3) + 8*(r>>2) + 4*hi
    if (mm == 2){
      #pragma unroll
      for (int r = 0; r < 16; ++r){
        int tok = (r&3) + 8*(r>>2) + 4*hi;
        tb[col*40 + tok]        = bf16b(acc0[r]);
        tb[(col+32)*40 + tok]   = bf16b(acc1[r]);
      }
      const int vrow = lane >> 2, ch = lane & 3;
      #pragma unroll
      for (int o2 = 0; o2 < 4; ++o2){
        int dv = o2*16 + vrow;
        u32x4 u = *(const u32x4*)(tb + dv*40 + ch*8);
        *(u32x4*)(Vtg + ((size_t)((b*8 + cb)*64 + dv))*4096 + ltok0 + ch*8) = u;
      }
    } else {
      uint16_t* G = mm ? Kg : Qg;
      #pragma unroll
      for (int r = 0; r < 16; ++r){
        int tok = (r&3) + 8*(r>>2) + 4*hi;
        tb[tok*72 + col]      = bf16b(acc0[r]);
        tb[tok*72 + 32 + col] = bf16b(acc1[r]);
      }
      const int rr2 = lane >> 3, ch2 = lane & 7;
      size_t base = (size_t)((b*8 + cb)*4096 + ltok0)*64;
      #pragma unroll
      for (int o2 = 0; o2 < 4; ++o2){
        int tok = o2*8 + rr2;
        u32x4 uu = *(const u32x4*)(tb + tok*72 + ch2*8);
        *(u32x4*)(G + base + (size_t)tok*64 + ch2*8) = uu;
      }
    }
  }
}

// ---------------- kernel 2: flash attention ----------------
// grid 512 (2 blocks/CU), 8 waves (512 thr) = 2 qh x 4 kvh streams.
// q=64/wave, KVBLK=32, kv-quarter 1024 per stream (32 tiles).
// LDS/stream/dbuf: K 4KB (XOR swz) + V^T 5KB (80B pad rows) = 9KB; 4 streams
// x 2 = 72KB -> 2 blocks/CU = 4 waves/SIMD.  No-max exp2 softmax -> kvh
// partials additive; 2-phase LDS tree merge at end.
__global__ __launch_bounds__(512,4) void attn_fa(char* __restrict__ ws){
  const int lane = threadIdx.x & 63;
  const int wave = threadIdx.x >> 6;            // 0..7
  const int qh = wave & 1, kvh = wave >> 1;     // q-half, kv-quarter
  const int u   = blockIdx.x >> 3;              // 0..63
  const int bh  = (blockIdx.x & 7) + ((u >> 5) << 3);
  const int qt  = u & 31;
  const int col = lane & 31, hi = lane >> 5;
  const int kxor = (col & 7) << 4;

  const uint16_t* Qg  = (const uint16_t*)(ws + WS_QG)  + (size_t)bh*262144;
  const uint16_t* Kg  = (const uint16_t*)(ws + WS_KG)  + (size_t)bh*262144;
  const uint16_t* Vtg = (const uint16_t*)(ws + WS_VTG) + (size_t)bh*262144;
  uint16_t* attn = (uint16_t*)(ws + WS_ATTN);

  // stream kvh region: [kvh*18432, +18432): dbuf d at +d*9216 (K 4KB, V 5KB)
  __shared__ __align__(16) char smem[73728];
  char* sb = smem + kvh*18432;

  const int qbase = qt*128 + qh*64;

  // Q fragments (B-operand): q = qbase + col + 32*qc, k = hi*8 + i (+16*ds)
  bf16x8 qf0[4], qf1[4];
  {
    const uint16_t* qr0 = Qg + (size_t)(qbase + col)*64 + hi*8;
    const uint16_t* qr1 = qr0 + 32*64;
    #pragma unroll
    for (int ds = 0; ds < 4; ++ds){
      qf0[ds] = *(const bf16x8*)(qr0 + ds*16);
      qf1[ds] = *(const bf16x8*)(qr1 + ds*16);
    }
  }

  // staging: wave stages half its stream's tile.
  // K: 2 instrs, rows qh*16 + i*8 + rr (rr=lane>>3), chunk ch=lane&7
  // V: 2 instrs, dv rows qh*32 + i*16 + (lane>>2), chunk c4=lane&3
  const int rr = lane >> 3, ch = lane & 7;
  const int vr = lane >> 2, c4 = lane & 3;
  const int krow0 = qh*16 + rr;                 // +8 for i=1
  const int vdv0  = qh*32 + vr;                 // +16 for i=1
  const uint16_t* kSrc = Kg  + (size_t)(kvh*1024 + krow0)*64 + ch*8;   // +t*2048 +i*512
  const uint16_t* vSrc = Vtg + (size_t)vdv0*4096 + kvh*1024 + c4*8;    // +t*32 +i*65536
  const int kDst0 = krow0*128 + ((ch*16) ^ ((krow0 & 7) << 4));
  const int kDst1 = (krow0+8)*128 + ((ch*16) ^ (((krow0+8) & 7) << 4));
  const int vDst0 = vdv0*80 + c4*16;            // V buffer at +4096
  const int vDst1 = (vdv0+16)*80 + c4*16;

  f32x16 ot00 = zero16(), ot01 = zero16(), ot10 = zero16(), ot11 = zero16();
  float rs0 = 0.0f, rs1 = 0.0f;

  u32x4 kA0, kA1, vA0, vA1, kB0, kB1, vB0, vB1;
  auto loadA = [&](int t){
    kA0 = *(const u32x4*)(kSrc + (size_t)t*2048);
    kA1 = *(const u32x4*)(kSrc + (size_t)t*2048 + 512);
    vA0 = *(const u32x4*)(vSrc + t*32);
    vA1 = *(const u32x4*)(vSrc + t*32 + (size_t)16*4096);
  };
  auto loadB = [&](int t){
    kB0 = *(const u32x4*)(kSrc + (size_t)t*2048);
    kB1 = *(const u32x4*)(kSrc + (size_t)t*2048 + 512);
    vB0 = *(const u32x4*)(vSrc + t*32);
    vB1 = *(const u32x4*)(vSrc + t*32 + (size_t)16*4096);
  };

  auto pack2 = [&](const f32x16& s, bf16x8& f0, bf16x8& f1){
    uint32_t w0 = cvtpk(s[0],  s[1]),  w1 = cvtpk(s[2],  s[3]);
    uint32_t w2 = cvtpk(s[4],  s[5]),  w3 = cvtpk(s[6],  s[7]);
    uint32_t w4 = cvtpk(s[8],  s[9]),  w5 = cvtpk(s[10], s[11]);
    uint32_t w6 = cvtpk(s[12], s[13]), w7 = cvtpk(s[14], s[15]);
    plswap(w0, w2); plswap(w1, w3); plswap(w4, w6); plswap(w5, w7);
    u32x4 u0; u0.x = w0; u0.y = w1; u0.z = w2; u0.w = w3;
    u32x4 u1; u1.x = w4; u1.y = w5; u1.z = w6; u1.w = w7;
    f0 = __builtin_bit_cast(bf16x8, u0);
    f1 = __builtin_bit_cast(bf16x8, u1);
  };

  #define WRITE_KV(dimm, K0, K1, V0, V1)                         \
    { char* wb = sb + (dimm)*9216;                               \
      *(u32x4*)(wb + kDst0) = K0;  *(u32x4*)(wb + kDst1) = K1;   \
      *(u32x4*)(wb + 4096 + vDst0) = V0;                         \
      *(u32x4*)(wb + 4096 + vDst1) = V1; }

  #define COMPUTE(dimm)                                                          \
    { const char* kb = sb + (dimm)*9216;                                         \
      const char* vb = kb + 4096;                                                \
      f32x16 sA = zero16(), sB = zero16();                                       \
      __builtin_amdgcn_s_setprio(1);                                             \
      _Pragma("unroll")                                                          \
      for (int ds = 0; ds < 4; ++ds){                                            \
        bf16x8 kf = *(const bf16x8*)(kb + col*128 + ((ds*32 + hi*16) ^ kxor));   \
        sA = __builtin_amdgcn_mfma_f32_32x32x16_bf16(kf, qf0[ds], sA, 0, 0, 0);  \
        sB = __builtin_amdgcn_mfma_f32_32x32x16_bf16(kf, qf1[ds], sB, 0, 0, 0);  \
      }                                                                          \
      __builtin_amdgcn_s_setprio(0);                                             \
      _Pragma("unroll")                                                          \
      for (int r = 0; r < 16; ++r) sA[r] = __builtin_amdgcn_exp2f(sA[r]);        \
      _Pragma("unroll")                                                          \
      for (int r = 0; r < 16; ++r) sB[r] = __builtin_amdgcn_exp2f(sB[r]);        \
      rs0 += sum16(sA);  rs1 += sum16(sB);                                       \
      bf16x8 pA0, pA1, pB0, pB1;                                                 \
      pack2(sA, pA0, pA1);  pack2(sB, pB0, pB1);                                 \
      __builtin_amdgcn_s_setprio(1);                                             \
      {                                                                          \
        bf16x8 vf;                                                               \
        vf = *(const bf16x8*)(vb + col*80 + hi*16);                              \
        ot00 = __builtin_amdgcn_mfma_f32_32x32x16_bf16(vf, pA0, ot00, 0, 0, 0);  \
        ot01 = __builtin_amdgcn_mfma_f32_32x32x16_bf16(vf, pB0, ot01, 0, 0, 0);  \
        vf = *(const bf16x8*)(vb + col*80 + 32 + hi*16);                         \
        ot00 = __builtin_amdgcn_mfma_f32_32x32x16_bf16(vf, pA1, ot00, 0, 0, 0);  \
        ot01 = __builtin_amdgcn_mfma_f32_32x32x16_bf16(vf, pB1, ot01, 0, 0, 0);  \
        vf = *(const bf16x8*)(vb + (col+32)*80 + hi*16);                         \
        ot10 = __builtin_amdgcn_mfma_f32_32x32x16_bf16(vf, pA0, ot10, 0, 0, 0);  \
        ot11 = __builtin_amdgcn_mfma_f32_32x32x16_bf16(vf, pB0, ot11, 0, 0, 0);  \
        vf = *(const bf16x8*)(vb + (col+32)*80 + 32 + hi*16);                    \
        ot10 = __builtin_amdgcn_mfma_f32_32x32x16_bf16(vf, pA1, ot10, 0, 0, 0);  \
        ot11 = __builtin_amdgcn_mfma_f32_32x32x16_bf16(vf, pB1, ot11, 0, 0, 0);  \
      }                                                                          \
      __builtin_amdgcn_s_setprio(0); }

  // pipeline: unroll-2, compile-time buffers, 1-deep reg prefetch
  loadA(0);
  WRITE_KV(0, kA0, kA1, vA0, vA1);
  loadA(1);
  bar_ws();

  #pragma unroll 1
  for (int t = 0; t < 32; t += 2){
    WRITE_KV(1, kA0, kA1, vA0, vA1);            // tile t+1
    { int tn = (t+2 < 32) ? t+2 : 31; loadB(tn); }
    COMPUTE(0);                                  // tile t
    bar_ws();
    WRITE_KV(0, kB0, kB1, vB0, vB1);            // tile t+2
    { int tn = (t+3 < 32) ? t+3 : 31; loadA(tn); }
    COMPUTE(1);                                  // tile t+1
    bar_ws();
  }

  // ---- kvh tree merge (additive) ----
  // region r = qh*2+j at smem + r*18432; per-lane 72 f32 (64 O + 2 l)
  {
    float* rg0 = (float*)(smem + (qh*2    )*18432) + lane*72;
    float* rg1 = (float*)(smem + (qh*2 + 1)*18432) + lane*72;
    auto dump = [&](float* m){
      #pragma unroll
      for (int j = 0; j < 4; ++j){
        *(f32x4*)(m +      4*j) = f32x4{ot00[4*j], ot00[4*j+1], ot00[4*j+2], ot00[4*j+3]};
        *(f32x4*)(m + 16 + 4*j) = f32x4{ot01[4*j], ot01[4*j+1], ot01[4*j+2], ot01[4*j+3]};
        *(f32x4*)(m + 32 + 4*j) = f32x4{ot10[4*j], ot10[4*j+1], ot10[4*j+2], ot10[4*j+3]};
        *(f32x4*)(m + 48 + 4*j) = f32x4{ot11[4*j], ot11[4*j+1], ot11[4*j+2], ot11[4*j+3]};
      }
      m[64] = rs0; m[65] = rs1;
    };
    auto addf = [&](const float* m){
      #pragma unroll
      for (int j = 0; j < 4; ++j){
        f32x4 v0 = *(const f32x4*)(m +      4*j);
        f32x4 v1 = *(const f32x4*)(m + 16 + 4*j);
        f32x4 v2 = *(const f32x4*)(m + 32 + 4*j);
        f32x4 v3 = *(const f32x4*)(m + 48 + 4*j);
        #pragma unroll
        for (int e = 0; e < 4; ++e){
          ot00[4*j+e] += v0[e]; ot01[4*j+e] += v1[e];
          ot10[4*j+e] += v2[e]; ot11[4*j+e] += v3[e];
        }
      }
      rs0 += m[64];  rs1 += m[65];
    };
    bar_ws();                       // loop epilogue barrier already, but be safe
    if (kvh == 1) dump(rg0);
    if (kvh == 3) dump(rg1);
    bar_ws();
    if (kvh == 0) addf(rg0);
    if (kvh == 2) addf(rg1);
    bar_ws();
    if (kvh == 2) dump(rg1);
    bar_ws();
    if (kvh == 0){
      addf(rg1);
      rs0 += __shfl_xor(rs0, 32);
      rs1 += __shfl_xor(rs1, 32);
      float inv0 = 1.0f / rs0, inv1 = 1.0f / rs1;

      // epilogue: normalize, per-wave LDS transpose, coalesced bf16 store
      uint32_t* ow = (uint32_t*)(smem + 36864 + qh*8448);   // [64 q][33] u32
      #pragma unroll
      for (int od = 0; od < 2; ++od){
        #pragma unroll
        for (int j = 0; j < 8; ++j){
          int p = (j&1) + 4*(j>>1) + 2*hi + 16*od;
          const f32x16& a0 = od ? ot10 : ot00;
          const f32x16& a1 = od ? ot11 : ot01;
          ow[(col     )*33 + p] = pk2(a0[2*j]*inv0, a0[2*j+1]*inv0);
          ow[(col + 32)*33 + p] = pk2(a1[2*j]*inv1, a1[2*j+1]*inv1);
        }
      }
      const int rrE = lane >> 3, chE = lane & 7;
      #pragma unroll
      for (int oo = 0; oo < 8; ++oo){
        int q = oo*8 + rrE;
        u32x4 uu = *(const u32x4*)(ow + q*33 + chE*4);
        size_t row = (size_t)((bh >> 3)*4096 + qbase + q);
        *(u32x4*)(attn + row*512 + (bh & 7)*64 + chE*8) = uu;
      }
    }
  }
  #undef WRITE_KV
  #undef COMPUTE
}

// ---------------- kernel 3: output projection + bias ----------------
__global__ __launch_bounds__(256) void out_proj(const char* __restrict__ ws,
                                                const float* __restrict__ bu,
                                                float* __restrict__ out){
  const int lane = threadIdx.x & 63;
  const int wave = blockIdx.x*4 + (threadIdx.x >> 6);   // 0..2047
  const int mt = wave >> 2, cb = wave & 3;
  const int rc = lane & 15, kg = lane >> 4;

  const uint16_t* attn = (const uint16_t*)(ws + WS_ATTN);
  const uint16_t* Wut  = (const uint16_t*)(ws + WS_WUT);

  const uint16_t* ar = attn + (size_t)(mt*16 + rc)*512 + kg*8;
  const uint16_t* bp = Wut  + (size_t)(cb*16 + rc)*512 + kg*8;

  f32x4 acc = {0.0f, 0.0f, 0.0f, 0.0f};
  #pragma unroll
  for (int ks = 0; ks < 16; ++ks){
    bf16x8 af = *(const bf16x8*)(ar + ks*32);
    bf16x8 bf = *(const bf16x8*)(bp + ks*32);
    acc = __builtin_amdgcn_mfma_f32_16x16x32_bf16(af, bf, acc, 0, 0, 0);
  }
  float bias = bu[cb*16 + rc];
  #pragma unroll
  for (int r = 0; r < 4; ++r){
    int orow = mt*16 + kg*4 + r;
    out[(size_t)orow*64 + cb*16 + rc] = acc[r] + bias;
  }
}

// ---------------- launch ----------------
extern "C" void kernel_launch(void* const* d_in, const int* in_sizes, int n_in,
                              void* d_out, int out_size, void* d_ws, size_t ws_size,
                              hipStream_t stream){
  const float* x  = (const float*)d_in[0];
  const float* Wq = (const float*)d_in[1];
  const float* Wk = (const float*)d_in[2];
  const float* Wv = (const float*)d_in[3];
  const float* Wu = (const float*)d_in[4];
  const float* bu = (const float*)d_in[5];
  char*  ws  = (char*)d_ws;
  float* out = (float*)d_out;

  prep_w  <<<dim3(512), dim3(256), 0, stream>>>(Wq, Wk, Wv, Wu, ws);
  qkv_proj<<<dim3(512), dim3(256), 0, stream>>>(x, ws);
  attn_fa <<<dim3(512), dim3(512), 0, stream>>>(ws);
  out_proj<<<dim3(512), dim3(256), 0, stream>>>(ws, bu, out);
}

// Round 9
// 184.636 us; speedup vs baseline: 6.2992x; 6.2992x over previous
//
#include <hip/hip_runtime.h>
#include <hip/hip_bf16.h>
#include <stdint.h>

// ---------------- types ----------------
typedef float    f32x16 __attribute__((ext_vector_type(16)));
typedef float    f32x4  __attribute__((ext_vector_type(4)));
typedef __bf16   bf16x8 __attribute__((ext_vector_type(8)));
typedef uint32_t u32x4  __attribute__((ext_vector_type(4)));

// ---------------- workspace layout (bytes) ----------------
#define WS_QG    0
#define WS_KG    8388608
#define WS_VTG   16777216
#define WS_ATTN  25165824
#define WS_WT    33554432
#define WS_WUT   33751040

__device__ __forceinline__ f32x16 zero16(){
  f32x16 z;
  #pragma unroll
  for (int i = 0; i < 16; ++i) z[i] = 0.0f;
  return z;
}

__device__ __forceinline__ uint16_t bf16b(float v){
  return __builtin_bit_cast(uint16_t, __float2bfloat16(v));
}

__device__ __forceinline__ uint32_t pk2(float a, float b){
  return (uint32_t)bf16b(a) | ((uint32_t)bf16b(b) << 16);
}

// packed f32->bf16 pair in ONE instruction (RNE)
__device__ __forceinline__ uint32_t cvtpk(float a, float b){
  uint32_t r;
  asm("v_cvt_pk_bf16_f32 %0, %1, %2" : "=v"(r) : "v"(a), "v"(b));
  return r;
}

__device__ __forceinline__ void plswap(uint32_t &a, uint32_t &b){
  asm volatile("v_permlane32_swap_b32 %0, %1" : "+v"(a), "+v"(b));
}

__device__ __forceinline__ float sum16(const f32x16& s){
  float a0 = (s[0]+s[1]) + (s[2]+s[3]),   a1 = (s[4]+s[5]) + (s[6]+s[7]);
  float a2 = (s[8]+s[9]) + (s[10]+s[11]), a3 = (s[12]+s[13]) + (s[14]+s[15]);
  return (a0 + a1) + (a2 + a3);
}

// async global->LDS, 16B/lane: LDS dst = (wave-uniform) l + lane*16
__device__ __forceinline__ void gl16(const uint16_t* g, char* l){
  __builtin_amdgcn_global_load_lds(
      (const __attribute__((address_space(1))) uint32_t*)g,
      (__attribute__((address_space(3))) uint32_t*)l, 16, 0, 0);
}

// raw barrier: drain own LDS ops, sync, compiler fence (vmcnt NOT drained).
__device__ __forceinline__ void bar_ws(){
  asm volatile("s_waitcnt lgkmcnt(0)" ::: "memory");
  __builtin_amdgcn_s_barrier();
  asm volatile("" ::: "memory");
}

// ---------------- kernel 0: weight prep ----------------
// Wf fragment layout: [mm][cb][ks][half][lane][8] so qkv_proj loads are
// fully coalesced (lane-contiguous 16B chunks).
__global__ void prep_w(const float* __restrict__ Wq, const float* __restrict__ Wk,
                       const float* __restrict__ Wv, const float* __restrict__ Wu,
                       char* __restrict__ ws){
  int tid = blockIdx.x * 256 + threadIdx.x;   // grid 512*256 = 131072
  if (tid < 98304){
    int j  = tid & 7;
    int ln = (tid >> 3) & 63;
    int hf = (tid >> 9) & 1;
    int ks = (tid >> 10) & 3;
    int cb = (tid >> 12) & 7;
    int mm = tid >> 15;
    int colW = ln & 31, hiW = ln >> 5;
    int k = ks*16 + hiW*8 + j;
    int e = cb*64 + colW + 32*hf;
    const float* W = (mm == 0) ? Wq : (mm == 1 ? Wk : Wv);
    float v = W[k*512 + e];
    if (mm == 0) v *= 0.18033688011112042f;   // (1/8) * log2(e) folded into Q
    ((uint16_t*)(ws + WS_WT))[tid] = bf16b(v);
  } else {
    int idx = tid - 98304;
    int c = idx & 63, e = idx >> 6;
    ((uint16_t*)(ws + WS_WUT))[c*512 + e] = bf16b(Wu[e*64 + c]);
  }
}

// ---------------- kernel 1: QKV projection (MFMA) ----------------
__global__ __launch_bounds__(256,2) void qkv_proj(const float* __restrict__ x,
                                                  char* __restrict__ ws){
  const int lane = threadIdx.x & 63;
  const int widx = threadIdx.x >> 6;
  const int x8 = blockIdx.x & 7;
  const int o  = blockIdx.x >> 3;        // 0..63
  const int rt   = x8*32 + (o >> 1);     // 0..255, XCD-pinned
  const int half = o & 1;
  const int col  = lane & 31, hi = lane >> 5;

  __shared__ __align__(16) uint16_t tbuf[4][2560];   // per-wave transpose buffer

  const uint16_t* Wf = (const uint16_t*)(ws + WS_WT);

  // A: row = lane&31, k = (lane>>5)*8 + i (+16*ks)  — computed ONCE
  bf16x8 af[4];
  {
    const float* xr = x + (size_t)(rt*32 + col)*64 + hi*8;
    #pragma unroll
    for (int ks = 0; ks < 4; ++ks){
      float4 a0 = *(const float4*)(xr + ks*16);
      float4 a1 = *(const float4*)(xr + ks*16 + 4);
      uint4 u;
      u.x = pk2(a0.x, a0.y); u.y = pk2(a0.z, a0.w);
      u.z = pk2(a1.x, a1.y); u.w = pk2(a1.z, a1.w);
      af[ks] = __builtin_bit_cast(bf16x8, u);
    }
  }

  uint16_t* Qg  = (uint16_t*)(ws + WS_QG);
  uint16_t* Kg  = (uint16_t*)(ws + WS_KG);
  uint16_t* Vtg = (uint16_t*)(ws + WS_VTG);
  uint16_t* tb  = tbuf[widx];
  const int b     = (rt*32) >> 12;
  const int ltok0 = (rt*32) & 4095;

  #pragma unroll
  for (int ti = 0; ti < 3; ++ti){
    const int rem = half*12 + widx*3 + ti;   // 0..23
    const int mm = rem >> 3, cb = rem & 7;

    f32x16 acc0 = zero16(), acc1 = zero16();
    {
      const uint16_t* wp = Wf + (size_t)((mm*8 + cb)*4)*1024 + lane*8;
      #pragma unroll
      for (int ks = 0; ks < 4; ++ks){
        bf16x8 b0 = *(const bf16x8*)(wp + ks*1024);
        bf16x8 b1 = *(const bf16x8*)(wp + ks*1024 + 512);
        acc0 = __builtin_amdgcn_mfma_f32_32x32x16_bf16(af[ks], b0, acc0, 0, 0, 0);
        acc1 = __builtin_amdgcn_mfma_f32_32x32x16_bf16(af[ks], b1, acc1, 0, 0, 0);
      }
    }

    // D: col = lane&31, row(tok) = (r&3) + 8*(r>>2) + 4*hi
    if (mm == 2){
      #pragma unroll
      for (int r = 0; r < 16; ++r){
        int tok = (r&3) + 8*(r>>2) + 4*hi;
        tb[col*40 + tok]        = bf16b(acc0[r]);
        tb[(col+32)*40 + tok]   = bf16b(acc1[r]);
      }
      const int vrow = lane >> 2, ch = lane & 3;
      #pragma unroll
      for (int o2 = 0; o2 < 4; ++o2){
        int dv = o2*16 + vrow;
        u32x4 u = *(const u32x4*)(tb + dv*40 + ch*8);
        *(u32x4*)(Vtg + ((size_t)((b*8 + cb)*64 + dv))*4096 + ltok0 + ch*8) = u;
      }
    } else {
      uint16_t* G = mm ? Kg : Qg;
      #pragma unroll
      for (int r = 0; r < 16; ++r){
        int tok = (r&3) + 8*(r>>2) + 4*hi;
        tb[tok*72 + col]      = bf16b(acc0[r]);
        tb[tok*72 + 32 + col] = bf16b(acc1[r]);
      }
      const int rr2 = lane >> 3, ch2 = lane & 7;
      size_t base = (size_t)((b*8 + cb)*4096 + ltok0)*64;
      #pragma unroll
      for (int o2 = 0; o2 < 4; ++o2){
        int tok = o2*8 + rr2;
        u32x4 uu = *(const u32x4*)(tb + tok*72 + ch2*8);
        *(u32x4*)(G + base + (size_t)tok*64 + ch2*8) = uu;
      }
    }
  }
}

// ---------------- kernel 2: flash attention ----------------
// grid 1024 (16 bh x 64 qt), XCD-pinned.  Block = 256 thr = 4 waves, each wave
// = one kv-QUARTER (1024 kv, 32 tiles of KVBLK=32) of the same 64-q tile.
// Private per-wave single-buffered LDS stream (K 4KB + V^T 4KB), staged with
// global_load_lds + pre-swizzled SOURCE (linear LDS dst), swizzled reads.
// NO barriers in main loop (same-wave vmcnt/lgkm ordering).  No-max exp2
// softmax -> kv partials additive; f32 LDS tree merge at end (7 barriers).
__global__ __launch_bounds__(256,3) void attn_fa(char* __restrict__ ws){
  const int lane = threadIdx.x & 63;
  const int kvh  = threadIdx.x >> 6;            // 0..3 kv-quarter
  const int u    = blockIdx.x >> 3;             // 0..127
  const int bh   = (blockIdx.x & 7) + ((u >> 6) << 3);
  const int qt   = u & 63;
  const int col = lane & 31, hi = lane >> 5;
  const int kxor = (col & 7) << 4;
  const int vxor = (col & 3) << 4;

  const uint16_t* Qg  = (const uint16_t*)(ws + WS_QG)  + (size_t)bh*262144;
  const uint16_t* Kg  = (const uint16_t*)(ws + WS_KG)  + (size_t)bh*262144;
  const uint16_t* Vtg = (const uint16_t*)(ws + WS_VTG) + (size_t)bh*262144;
  uint16_t* attn = (uint16_t*)(ws + WS_ATTN);

  // 4 private regions of 9216B: K @0 (4KB), V @4096 (4KB), spare @8192
  __shared__ __align__(16) char smem[36864];
  char* kb = smem + kvh*9216;
  char* vb = kb + 4096;

  const int qbase = qt*64;

  // Q fragments (B-operand): q = qbase + col (+32), k = hi*8 + i (+16*ds)
  bf16x8 qf0[4], qf1[4];
  {
    const uint16_t* qr0 = Qg + (size_t)(qbase + col)*64 + hi*8;
    const uint16_t* qr1 = qr0 + 2048;
    #pragma unroll
    for (int ds = 0; ds < 4; ++ds){
      qf0[ds] = *(const bf16x8*)(qr0 + ds*16);
      qf1[ds] = *(const bf16x8*)(qr1 + ds*16);
    }
  }

  // staging sources, pre-swizzled chunk index (involution):
  // K: LDS[row][ch] = K[row][ch ^ (row&7)] ; V: LDS[dv][c4] = V[dv][c4 ^ (dv&3)]
  const int rr = lane >> 3, ch = lane & 7;      // K row-in-8group, 16B chunk
  const int vr = lane >> 2, c4 = lane & 3;      // V dv-in-16group, 16B chunk
  const uint16_t* kS = Kg  + (size_t)(kvh*1024 + rr)*64 + (ch ^ rr)*8;
  const uint16_t* vS = Vtg + (size_t)vr*4096 + kvh*1024 + (c4 ^ (vr & 3))*8;

  f32x16 ot00 = zero16(), ot01 = zero16(), ot10 = zero16(), ot11 = zero16();
  float rs0 = 0.0f, rs1 = 0.0f;

  #define STAGE(T){                                                   \
    const uint16_t* k_ = kS + (size_t)(T)*2048;                       \
    gl16(k_,        kb);        gl16(k_ + 512,  kb + 1024);           \
    gl16(k_ + 1024, kb + 2048); gl16(k_ + 1536, kb + 3072);           \
    const uint16_t* v_ = vS + (T)*32;                                 \
    gl16(v_,          vb);        gl16(v_ + 65536,  vb + 1024);       \
    gl16(v_ + 131072, vb + 2048); gl16(v_ + 196608, vb + 3072); }

  STAGE(0);

  #pragma unroll 1
  for (int t = 0; t < 32; ++t){
    asm volatile("s_waitcnt vmcnt(0)" ::: "memory");   // tile t landed in LDS

    // S^T(32kv x 64q) = K-tile · Q^T
    f32x16 sA = zero16(), sB = zero16();
    __builtin_amdgcn_s_setprio(1);
    #pragma unroll
    for (int ds = 0; ds < 4; ++ds){
      bf16x8 kf = *(const bf16x8*)(kb + col*128 + ((ds*32 + hi*16) ^ kxor));
      sA = __builtin_amdgcn_mfma_f32_32x32x16_bf16(kf, qf0[ds], sA, 0, 0, 0);
      sB = __builtin_amdgcn_mfma_f32_32x32x16_bf16(kf, qf1[ds], sB, 0, 0, 0);
    }
    __builtin_amdgcn_s_setprio(0);

    #pragma unroll
    for (int r = 0; r < 16; ++r) sA[r] = __builtin_amdgcn_exp2f(sA[r]);
    #pragma unroll
    for (int r = 0; r < 16; ++r) sB[r] = __builtin_amdgcn_exp2f(sB[r]);
    rs0 += sum16(sA);
    rs1 += sum16(sB);

    bf16x8 pA0, pA1, pB0, pB1;
    {
      uint32_t w0 = cvtpk(sA[0],  sA[1]),  w1 = cvtpk(sA[2],  sA[3]);
      uint32_t w2 = cvtpk(sA[4],  sA[5]),  w3 = cvtpk(sA[6],  sA[7]);
      uint32_t w4 = cvtpk(sA[8],  sA[9]),  w5 = cvtpk(sA[10], sA[11]);
      uint32_t w6 = cvtpk(sA[12], sA[13]), w7 = cvtpk(sA[14], sA[15]);
      plswap(w0, w2); plswap(w1, w3); plswap(w4, w6); plswap(w5, w7);
      u32x4 u0; u0.x = w0; u0.y = w1; u0.z = w2; u0.w = w3;
      u32x4 u1; u1.x = w4; u1.y = w5; u1.z = w6; u1.w = w7;
      pA0 = __builtin_bit_cast(bf16x8, u0);
      pA1 = __builtin_bit_cast(bf16x8, u1);
      uint32_t y0 = cvtpk(sB[0],  sB[1]),  y1 = cvtpk(sB[2],  sB[3]);
      uint32_t y2 = cvtpk(sB[4],  sB[5]),  y3 = cvtpk(sB[6],  sB[7]);
      uint32_t y4 = cvtpk(sB[8],  sB[9]),  y5 = cvtpk(sB[10], sB[11]);
      uint32_t y6 = cvtpk(sB[12], sB[13]), y7 = cvtpk(sB[14], sB[15]);
      plswap(y0, y2); plswap(y1, y3); plswap(y4, y6); plswap(y5, y7);
      u32x4 u2; u2.x = y0; u2.y = y1; u2.z = y2; u2.w = y3;
      u32x4 u3; u3.x = y4; u3.y = y5; u3.z = y6; u3.w = y7;
      pB0 = __builtin_bit_cast(bf16x8, u2);
      pB1 = __builtin_bit_cast(bf16x8, u3);
    }

    // O^T(64dv x 64q) += V^T-tile(64dv x 32kv) · P
    __builtin_amdgcn_s_setprio(1);
    #pragma unroll
    for (int ks = 0; ks < 2; ++ks){
      bf16x8 pa = ks ? pA1 : pA0;
      bf16x8 pb = ks ? pB1 : pB0;
      bf16x8 v0 = *(const bf16x8*)(vb + col*64 + ((ks*32 + hi*16) ^ vxor));
      ot00 = __builtin_amdgcn_mfma_f32_32x32x16_bf16(v0, pa, ot00, 0, 0, 0);
      ot01 = __builtin_amdgcn_mfma_f32_32x32x16_bf16(v0, pb, ot01, 0, 0, 0);
      bf16x8 v1 = *(const bf16x8*)(vb + (col+32)*64 + ((ks*32 + hi*16) ^ vxor));
      ot10 = __builtin_amdgcn_mfma_f32_32x32x16_bf16(v1, pa, ot10, 0, 0, 0);
      ot11 = __builtin_amdgcn_mfma_f32_32x32x16_bf16(v1, pb, ot11, 0, 0, 0);
    }
    __builtin_amdgcn_s_setprio(0);

    // all ds_reads of tile t retired before DMA overwrites the buffer
    asm volatile("s_waitcnt lgkmcnt(0)" ::: "memory");
    if (t < 31) STAGE(t+1);
  }
  #undef STAGE

  // ---- kv-quarter tree merge (additive; f32; reuses dead stream LDS) ----
  {
    float* mOwn = (float*)(smem + kvh*9216) + lane*34;
    float* mUp  = (float*)(smem + ((kvh < 3 ? kvh+1 : 3))*9216) + lane*34;
    float* mR2  = (float*)(smem + 2*9216) + lane*34;
    float* mR3  = (float*)(smem + 3*9216) + lane*34;

    auto dumpH0 = [&](float* m){
      #pragma unroll
      for (int j = 0; j < 4; ++j){
        *(f32x4*)(m +      4*j) = f32x4{ot00[4*j], ot00[4*j+1], ot00[4*j+2], ot00[4*j+3]};
        *(f32x4*)(m + 16 + 4*j) = f32x4{ot01[4*j], ot01[4*j+1], ot01[4*j+2], ot01[4*j+3]};
      }
      m[32] = rs0; m[33] = rs1;
    };
    auto dumpH1 = [&](float* m){
      #pragma unroll
      for (int j = 0; j < 4; ++j){
        *(f32x4*)(m +      4*j) = f32x4{ot10[4*j], ot10[4*j+1], ot10[4*j+2], ot10[4*j+3]};
        *(f32x4*)(m + 16 + 4*j) = f32x4{ot11[4*j], ot11[4*j+1], ot11[4*j+2], ot11[4*j+3]};
      }
    };
    auto addH0 = [&](const float* m){
      #pragma unroll
      for (int j = 0; j < 4; ++j){
        f32x4 a = *(const f32x4*)(m + 4*j);
        f32x4 b = *(const f32x4*)(m + 16 + 4*j);
        #pragma unroll
        for (int e = 0; e < 4; ++e){ ot00[4*j+e] += a[e]; ot01[4*j+e] += b[e]; }
      }
      rs0 += m[32]; rs1 += m[33];
    };
    auto addH1 = [&](const float* m){
      #pragma unroll
      for (int j = 0; j < 4; ++j){
        f32x4 a = *(const f32x4*)(m + 4*j);
        f32x4 b = *(const f32x4*)(m + 16 + 4*j);
        #pragma unroll
        for (int e = 0; e < 4; ++e){ ot10[4*j+e] += a[e]; ot11[4*j+e] += b[e]; }
      }
    };

    if (kvh & 1) dumpH0(mOwn);        // 1 -> r1, 3 -> r3 (own region, no race)
    bar_ws();
    if (!(kvh & 1)) addH0(mUp);       // 0 += r1, 2 += r3
    bar_ws();
    if (kvh & 1) dumpH1(mOwn);
    bar_ws();
    if (!(kvh & 1)) addH1(mUp);
    bar_ws();
    if (kvh == 2){ dumpH0(mOwn); dumpH1(mR3); }   // 2 -> r2 (h0), r3 (h1)
    bar_ws();
    if (kvh == 0){
      addH0(mR2); addH1(mR3);

      rs0 += __shfl_xor(rs0, 32);
      rs1 += __shfl_xor(rs1, 32);
      float inv0 = 1.0f / rs0, inv1 = 1.0f / rs1;

      // epilogue: normalize, LDS transpose in region 0, coalesced bf16 store
      uint32_t* ow = (uint32_t*)smem;              // [64 q][33] u32 = 8448B
      #pragma unroll
      for (int od = 0; od < 2; ++od){
        #pragma unroll
        for (int j = 0; j < 8; ++j){
          int p = (j&1) + 4*(j>>1) + 2*hi + 16*od;
          const f32x16& a0 = od ? ot10 : ot00;
          const f32x16& a1 = od ? ot11 : ot01;
          ow[col*33 + p]      = pk2(a0[2*j]*inv0, a0[2*j+1]*inv0);
          ow[(col+32)*33 + p] = pk2(a1[2*j]*inv1, a1[2*j+1]*inv1);
        }
      }
      const int rrE = lane >> 3, chE = lane & 7;
      #pragma unroll
      for (int oo = 0; oo < 8; ++oo){
        int q = oo*8 + rrE;
        u32x4 uu = *(const u32x4*)(ow + q*33 + chE*4);
        size_t row = (size_t)((bh >> 3)*4096 + qbase + q);
        *(u32x4*)(attn + row*512 + (bh & 7)*64 + chE*8) = uu;
      }
    }
  }
}

// ---------------- kernel 3: output projection + bias ----------------
__global__ __launch_bounds__(256) void out_proj(const char* __restrict__ ws,
                                                const float* __restrict__ bu,
                                                float* __restrict__ out){
  const int lane = threadIdx.x & 63;
  const int wave = blockIdx.x*4 + (threadIdx.x >> 6);   // 0..2047
  const int mt = wave >> 2, cb = wave & 3;
  const int rc = lane & 15, kg = lane >> 4;

  const uint16_t* attn = (const uint16_t*)(ws + WS_ATTN);
  const uint16_t* Wut  = (const uint16_t*)(ws + WS_WUT);

  const uint16_t* ar = attn + (size_t)(mt*16 + rc)*512 + kg*8;
  const uint16_t* bp = Wut  + (size_t)(cb*16 + rc)*512 + kg*8;

  f32x4 acc = {0.0f, 0.0f, 0.0f, 0.0f};
  #pragma unroll
  for (int ks = 0; ks < 16; ++ks){
    bf16x8 af = *(const bf16x8*)(ar + ks*32);
    bf16x8 bf = *(const bf16x8*)(bp + ks*32);
    acc = __builtin_amdgcn_mfma_f32_16x16x32_bf16(af, bf, acc, 0, 0, 0);
  }
  float bias = bu[cb*16 + rc];
  #pragma unroll
  for (int r = 0; r < 4; ++r){
    int orow = mt*16 + kg*4 + r;
    out[(size_t)orow*64 + cb*16 + rc] = acc[r] + bias;
  }
}

// ---------------- launch ----------------
extern "C" void kernel_launch(void* const* d_in, const int* in_sizes, int n_in,
                              void* d_out, int out_size, void* d_ws, size_t ws_size,
                              hipStream_t stream){
  const float* x  = (const float*)d_in[0];
  const float* Wq = (const float*)d_in[1];
  const float* Wk = (const float*)d_in[2];
  const float* Wv = (const float*)d_in[3];
  const float* Wu = (const float*)d_in[4];
  const float* bu = (const float*)d_in[5];
  char*  ws  = (char*)d_ws;
  float* out = (float*)d_out;

  prep_w  <<<dim3(512),  dim3(256), 0, stream>>>(Wq, Wk, Wv, Wu, ws);
  qkv_proj<<<dim3(512),  dim3(256), 0, stream>>>(x, ws);
  attn_fa <<<dim3(1024), dim3(256), 0, stream>>>(ws);
  out_proj<<<dim3(512),  dim3(256), 0, stream>>>(ws, bu, out);
}